// Round 4
// baseline (1178.706 us; speedup 1.0000x reference)
//
#include <hip/hip_runtime.h>
#include <hip/hip_bf16.h>
#include <math.h>

// ---------------------------------------------------------------------------
// LinearCrossEntropy via MX-fp8 MFMA (16x16x128 f8f6f4, uniform HW scales).
// R8: 128x128 double-buffered 2-phase GEMM with issue-early staging.
//   R7 post-mortem: 1 block/CU lockstep 8-wave pipeline exposed every stall
//   (MfmaUtil 21% < R4's 31%). R8 keeps R4's 128^2 tile / 4 waves but:
//   * double-buffers LDS (2x16KB A + 2x16KB B = 64 KB -> 2 blocks/CU
//     co-residency, launch_bounds(256,2); live regs ~150 << 256 cap)
//   * issues next K-tile's global_load_lds BEFORE compute; vmcnt(0) lands
//     after ~1000 cyc of ds_read+MFMA cover (R4 stalled on it immediately)
//   * keeps T1 XCD swizzle, T2 fp8 XOR LDS swizzle, T5 setprio, fused
//     sum-exp + target-logit epilogue.
// Dispatches: memset, cast_all, gemm, lse_finish, final_scalar.
// ---------------------------------------------------------------------------

#define BM 128
#define BN 128
#define BKB 128  // K elements (= bytes, fp8) per K-tile

typedef int   i32x8 __attribute__((ext_vector_type(8)));
typedef float f32x4 __attribute__((ext_vector_type(4)));

__device__ __forceinline__ void load_lds16(const void* g, void* l) {
    __builtin_amdgcn_global_load_lds(
        (const __attribute__((address_space(1))) void*)g,
        (__attribute__((address_space(3))) void*)l, 16, 0, 0);
}

// ---- fp8 e4m3fn conversion -------------------------------------------------
__device__ __forceinline__ unsigned char f2e4m3_sw(float x) {
    unsigned u = __float_as_uint(x);
    unsigned s = (u >> 24) & 0x80;
    float ax = __uint_as_float(u & 0x7fffffff);
    if (ax != ax) return (unsigned char)(s | 0x7f);
    if (ax >= 448.f) return (unsigned char)(s | 0x7e);
    if (ax < 0.0009765625f) return (unsigned char)s;      // < 2^-10 -> 0
    if (ax < 0.015625f) {                                 // subnormal, ulp 2^-9
        int n = (int)rintf(ax * 512.f);
        return (unsigned char)(s | n);
    }
    int e = (int)((u >> 23) & 0xff) - 127;
    unsigned m = u & 0x7fffff;
    unsigned keep = m >> 20, rest = m & 0xfffff;
    if (rest > 0x80000u || (rest == 0x80000u && (keep & 1))) keep++;
    if (keep == 8) { keep = 0; e++; if (e > 8) return (unsigned char)(s | 0x7e); }
    return (unsigned char)(s | ((e + 7) << 3) | keep);
}

__device__ __forceinline__ unsigned int pk4_fp8(float a, float b, float c, float d) {
#if __has_builtin(__builtin_amdgcn_cvt_pk_fp8_f32)
    int v = __builtin_amdgcn_cvt_pk_fp8_f32(a, b, 0, false);  // bytes 0,1
    v = __builtin_amdgcn_cvt_pk_fp8_f32(c, d, v, true);       // bytes 2,3
    return (unsigned int)v;
#else
    return (unsigned int)f2e4m3_sw(a) | ((unsigned int)f2e4m3_sw(b) << 8) |
           ((unsigned int)f2e4m3_sw(c) << 16) | ((unsigned int)f2e4m3_sw(d) << 24);
#endif
}

// Combined cast: [0,ne) from e (scale 1), [ne, ne+ncd) from c (scale 16,
// zero-fill past ncs). All boundaries multiples of 8.
__global__ void cast_all_fp8(const float* __restrict__ e,
                             const float* __restrict__ c,
                             unsigned char* __restrict__ e_f8,
                             unsigned char* __restrict__ c_f8,
                             long ne, long ncs, long ncd) {
    long i8 = ((long)blockIdx.x * blockDim.x + threadIdx.x) * 8;
    if (i8 >= ne + ncd) return;
    const float* src;
    unsigned char* dst;
    float scale;
    bool zero = false;
    if (i8 < ne) {
        src = e + i8; dst = e_f8 + i8; scale = 1.0f;
    } else {
        long j8 = i8 - ne;
        dst = c_f8 + j8; scale = 16.0f;
        src = c + j8;
        zero = (j8 + 7 >= ncs);
    }
    uint2 o;
    if (!zero) {
        float4 v0 = *(const float4*)(src);
        float4 v1 = *(const float4*)(src + 4);
        o.x = pk4_fp8(v0.x * scale, v0.y * scale, v0.z * scale, v0.w * scale);
        o.y = pk4_fp8(v1.x * scale, v1.y * scale, v1.z * scale, v1.w * scale);
    } else {
        o.x = o.y = 0u;
    }
    *(uint2*)dst = o;
}

// ---- GEMM 128x128, double-buffered 2-phase, fused LSE epilogue -------------
// E: [N][D] fp8, C: [Vpad][D] fp8 (zero-pad rows).
// LDS: A 2x16KB at [0,32768), B 2x16KB at [32768,65536).
// Row r chunk c (16B) stored at chunk position c^(r&7) (XOR swizzle), achieved
// by pre-swizzling the per-lane GLOBAL source address (linear LDS dest).
// Staging unit: 256 thr x 16B = 4 KB = 32 rows; tile = 4 units. Per wave:
// 4 A-loads + 4 B-loads (vmcnt ops) per K-tile.

// whole A K-tile (4 units of 32 rows)
#define STG_A(k, b) do {                                                      \
    const unsigned char* _s = gA + (size_t)(k) * 128;                         \
    load_lds16(_s,              lA + (b) * 16384);                            \
    load_lds16(_s +     row32,  lA + (b) * 16384 + 4096);                     \
    load_lds16(_s + 2 * row32,  lA + (b) * 16384 + 8192);                     \
    load_lds16(_s + 3 * row32,  lA + (b) * 16384 + 12288);                    \
} while (0)

#define STG_B(k, b) do {                                                      \
    const unsigned char* _s = gB + (size_t)(k) * 128;                         \
    load_lds16(_s,              lB + (b) * 16384);                            \
    load_lds16(_s +     row32,  lB + (b) * 16384 + 4096);                     \
    load_lds16(_s + 2 * row32,  lB + (b) * 16384 + 8192);                     \
    load_lds16(_s + 3 * row32,  lB + (b) * 16384 + 12288);                    \
} while (0)

#define LDA_FRAG(dst, ti, b) do {                                             \
    const unsigned char* _pr = ldsA + (b) * 16384 + (wr0 + (ti) * 16 + lm) * 128; \
    int4 _lo = *(const int4*)(_pr + c0);                                      \
    int4 _hi = *(const int4*)(_pr + c1);                                      \
    dst = (i32x8){_lo.x, _lo.y, _lo.z, _lo.w, _hi.x, _hi.y, _hi.z, _hi.w};    \
} while (0)

#define LDB_FRAG(dst, tj, b) do {                                             \
    const unsigned char* _pr = ldsB + (b) * 16384 + (wc0 + (tj) * 16 + lm) * 128; \
    int4 _lo = *(const int4*)(_pr + c0);                                      \
    int4 _hi = *(const int4*)(_pr + c1);                                      \
    dst = (i32x8){_lo.x, _lo.y, _lo.z, _lo.w, _hi.x, _hi.y, _hi.z, _hi.w};    \
} while (0)

#define MFMA1(a, bfr, c) __builtin_amdgcn_mfma_scale_f32_16x16x128_f8f6f4(    \
    (a), (bfr), (c), 0, 0, 0, sA, 0, sB)

__global__ __launch_bounds__(256, 2)
void gemm_lse_partial(const unsigned char* __restrict__ E,
                      const unsigned char* __restrict__ C,
                      const float* __restrict__ bias,
                      const int* __restrict__ targets,
                      float* __restrict__ row_sum,
                      float* __restrict__ tgt,
                      int N, int D, int V, int mtiles) {
    __shared__ unsigned char smem[65536];
    unsigned char* ldsA = smem;             // 2 x 16 KB
    unsigned char* ldsB = smem + 32768;     // 2 x 16 KB

    const int t_ = threadIdx.x;
    const int w  = t_ >> 6;           // 0..3
    const int l  = t_ & 63;
    const int quad = l >> 4;
    const int lm = l & 15;
    const int wr0 = (w >> 1) * 64;    // 2 row-groups of 64
    const int wc0 = (w & 1) * 64;     // 2 col-groups of 64
    const int c0 = ((quad << 1) ^ (lm & 7)) << 4;
    const int c1 = c0 ^ 16;

    // XCD-bijective block swizzle (nwg % 8 == 0 here; identity fallback else).
    // Within an XCD chunk, mt varies fastest -> ~64 resident blocks/XCD share
    // one B panel (L2-hot).
    const int nwg = (int)gridDim.x;
    int swz;
    if (nwg & 7) swz = (int)blockIdx.x;
    else         swz = ((int)blockIdx.x & 7) * (nwg >> 3) + ((int)blockIdx.x >> 3);
    const int mt = swz % mtiles;
    const int vt = swz / mtiles;
    const int m0 = mt * BM;
    const int v0 = vt * BN;

    // staging map: thread t -> row sr = t>>3 (32 rows/unit), stored chunk t&7
    // (LDS linear per wave: base + lane*16). Global chunk pre-swizzled:
    // gc = (t&7) ^ (sr&7); unit stride 32 rows => (row&7) preserved.
    const int sr = t_ >> 3;                    // 0..31
    const int gc = (t_ & 7) ^ (sr & 7);
    const unsigned char* gA = E + (size_t)(m0 + sr) * D + gc * 16;
    const unsigned char* gB = C + (size_t)(v0 + sr) * D + gc * 16;
    unsigned char* lA = ldsA + w * 1024;       // wave-uniform LDS base
    unsigned char* lB = ldsB + w * 1024;
    const size_t row32 = (size_t)32 * D;

    f32x4 acc[4][4] = {};
    const int sA = 127;  // e8m0 2^0   (E)
    const int sB = 123;  // e8m0 2^-4  (undoes *16 in cast of C)
    const int KT = D / BKB;    // 8 K-tiles

    // ---- prologue: K-tile 0 into buf0 --------------------------------------
    STG_A(0, 0); STG_B(0, 0);
    asm volatile("s_waitcnt vmcnt(0)" ::: "memory");
    __builtin_amdgcn_s_barrier();
    asm volatile("" ::: "memory");

    // ---- main loop: issue-early stage, compute, cheap drain ----------------
    int buf = 0;
    for (int kt = 0; kt < KT; ++kt) {
        const bool more = (kt < KT - 1);
        if (more) { STG_A(kt + 1, buf ^ 1); STG_B(kt + 1, buf ^ 1); }

        i32x8 af0, af1, af2, af3, bf0, bf1, bf2, bf3;
        LDA_FRAG(af0, 0, buf); LDA_FRAG(af1, 1, buf);
        LDA_FRAG(af2, 2, buf); LDA_FRAG(af3, 3, buf);
        LDB_FRAG(bf0, 0, buf); LDB_FRAG(bf1, 1, buf);
        LDB_FRAG(bf2, 2, buf); LDB_FRAG(bf3, 3, buf);

        asm volatile("s_waitcnt lgkmcnt(0)" ::: "memory");
        __builtin_amdgcn_sched_barrier(0);
        __builtin_amdgcn_s_setprio(1);
        acc[0][0] = MFMA1(af0, bf0, acc[0][0]);
        acc[0][1] = MFMA1(af0, bf1, acc[0][1]);
        acc[0][2] = MFMA1(af0, bf2, acc[0][2]);
        acc[0][3] = MFMA1(af0, bf3, acc[0][3]);
        acc[1][0] = MFMA1(af1, bf0, acc[1][0]);
        acc[1][1] = MFMA1(af1, bf1, acc[1][1]);
        acc[1][2] = MFMA1(af1, bf2, acc[1][2]);
        acc[1][3] = MFMA1(af1, bf3, acc[1][3]);
        acc[2][0] = MFMA1(af2, bf0, acc[2][0]);
        acc[2][1] = MFMA1(af2, bf1, acc[2][1]);
        acc[2][2] = MFMA1(af2, bf2, acc[2][2]);
        acc[2][3] = MFMA1(af2, bf3, acc[2][3]);
        acc[3][0] = MFMA1(af3, bf0, acc[3][0]);
        acc[3][1] = MFMA1(af3, bf1, acc[3][1]);
        acc[3][2] = MFMA1(af3, bf2, acc[3][2]);
        acc[3][3] = MFMA1(af3, bf3, acc[3][3]);
        __builtin_amdgcn_s_setprio(0);
        __builtin_amdgcn_sched_barrier(0);

        if (more) {
            // stage loads were issued ~1 K-tile of compute ago -> cheap drain
            asm volatile("s_waitcnt vmcnt(0)" ::: "memory");
            __builtin_amdgcn_s_barrier();
            asm volatile("" ::: "memory");
            buf ^= 1;
        }
    }

    // ---- epilogue: bias + exp + target extraction + per-row sums -----------
    // acc[ti][tj][r] -> row = wr0+ti*16+quad*4+r, col = wc0+tj*16+lm
    __syncthreads();                 // all LDS reads done; re-alias tile LDS
    float* red = (float*)smem;       // [2 col-wave-groups][128 rows]

    float bv[4];
#pragma unroll
    for (int tj = 0; tj < 4; tj++) {
        int col = v0 + wc0 + tj * 16 + lm;
        bv[tj] = (col < V) ? bias[col] : -INFINITY;
    }
#pragma unroll
    for (int ti = 0; ti < 4; ti++) {
#pragma unroll
        for (int r = 0; r < 4; r++) {
            const int rl = wr0 + ti * 16 + quad * 4 + r;
            const int tl = targets[m0 + rl] - v0 - wc0;
            float s = 0.f;
#pragma unroll
            for (int tj = 0; tj < 4; tj++) {
                float v = acc[ti][tj][r] + bv[tj];   // pad col: exp(-inf)=0
                s += __expf(v);
                if (tj * 16 + lm == tl) tgt[m0 + rl] = v;
            }
#pragma unroll
            for (int off = 1; off < 16; off <<= 1)
                s += __shfl_xor(s, off, 64);
            if (lm == 0) red[(w & 1) * 128 + rl] = s;
        }
    }
    __syncthreads();
    if (t_ < BM)
        atomicAdd(&row_sum[m0 + t_], red[t_] + red[128 + t_]);
}

// Finish: nll per row, block-reduce, atomic accumulate (sum, count).
__global__ void lse_finish(const float* __restrict__ row_sum,
                           const float* __restrict__ tgt,
                           const int* __restrict__ targets,
                           float* __restrict__ gacc, int N) {
    __shared__ float sred[8];
    int r = blockIdx.x * 256 + threadIdx.x;
    float nll = 0.f, cnt = 0.f;
    if (r < N) {
        int tg = targets[r];
        if (tg != -100) { nll = logf(row_sum[r]) - tgt[r]; cnt = 1.f; }
    }
#pragma unroll
    for (int off = 32; off; off >>= 1) {
        nll += __shfl_xor(nll, off, 64);
        cnt += __shfl_xor(cnt, off, 64);
    }
    int w = threadIdx.x >> 6, l = threadIdx.x & 63;
    if (l == 0) { sred[w] = nll; sred[4 + w] = cnt; }
    __syncthreads();
    if (threadIdx.x == 0) {
        atomicAdd(gacc, sred[0] + sred[1] + sred[2] + sred[3]);
        atomicAdd(gacc + 1, sred[4] + sred[5] + sred[6] + sred[7]);
    }
}

__global__ void final_scalar(const float* __restrict__ gacc, float* __restrict__ out) {
    out[0] = gacc[0] / fmaxf(gacc[1], 1.f);
}

extern "C" void kernel_launch(void* const* d_in, const int* in_sizes, int n_in,
                              void* d_out, int out_size, void* d_ws, size_t ws_size,
                              hipStream_t stream) {
    const float* e       = (const float*)d_in[0];
    const float* c       = (const float*)d_in[1];
    const int*   targets = (const int*)d_in[2];
    const float* bias    = (const float*)d_in[3];
    float* out = (float*)d_out;

    const int N = in_sizes[2];            // 8192
    const int V = in_sizes[3];            // 50257
    const int D = in_sizes[0] / N;        // 1024
    const int mtiles = N / BM;            // 64
    const int vtiles = (V + BN - 1) / BN; // 393
    const long Vpad = (long)vtiles * BN;  // 50304

    char* ws = (char*)d_ws;
    size_t off = 0;
    auto alloc = [&](size_t bytes) {
        void* p = ws + off;
        off += (bytes + 255) & ~(size_t)255;
        return p;
    };
    unsigned char* e_f8 = (unsigned char*)alloc((size_t)N * D);
    unsigned char* c_f8 = (unsigned char*)alloc((size_t)Vpad * D);
    float* row_sum = (float*)alloc((size_t)N * 4);   // zeroed below
    float* gacc    = (float*)alloc(8);               // adjacent to row_sum
    float* tgt     = (float*)alloc((size_t)N * 4);

    // one memset covers row_sum (N*4, 256-rounded) + gacc
    hipMemsetAsync(row_sum, 0, (size_t)N * 4 + 256 + 8, stream);

    const long ne  = (long)N * D;
    const long ncs = (long)V * D;
    const long ncd = Vpad * D;
    const long tot8 = (ne + ncd) / 8;
    cast_all_fp8<<<(int)((tot8 + 255) / 256), 256, 0, stream>>>(
        e, c, e_f8, c_f8, ne, ncs, ncd);

    const int nblk = mtiles * vtiles;     // 25152 (divisible by 8)
    gemm_lse_partial<<<nblk, 256, 0, stream>>>(e_f8, c_f8, bias, targets,
                                               row_sum, tgt, N, D, V, mtiles);

    lse_finish<<<(N + 255) / 256, 256, 0, stream>>>(row_sum, tgt, targets, gacc, N);
    final_scalar<<<1, 1, 0, stream>>>(gacc, out);
}

// Round 5
// 1072.519 us; speedup vs baseline: 1.0990x; 1.0990x over previous
//
#include <hip/hip_runtime.h>
#include <hip/hip_bf16.h>
#include <math.h>

// ---------------------------------------------------------------------------
// LinearCrossEntropy via MX-fp8 MFMA (16x16x128 f8f6f4, uniform HW scales).
// R9: R8's double-buffered issue-early GEMM, XCD swizzle REMOVED.
//   R8 post-mortem: the chunked XCD swizzle gave each XCD a private vtile
//   range -> each XCD re-scanned the full 8 MB E per vtile outside its 4 MB
//   L2 -> FETCH_SIZE 206 MB -> 1.64 GB (8x) and the L3-latency fills landed
//   inside the vmcnt(0) drain (MfmaUtil 19% < R4's 31%). Data is L3-fit
//   (60 MB), so XCD swizzle costs here (guide m160). Restore R4's 2D grid
//   (mt = blockIdx.x fastest: whole GPU shares one hot B panel + L2/L3-hot E).
//   Keep: 2x(16+16) KB double-buffered LDS (2 blocks/CU), issue-next-tile
//   stage BEFORE compute, T2 fp8 XOR LDS swizzle, T5 setprio, fused
//   sum-exp + target-logit epilogue.
// Dispatches: memset, cast_all, gemm, lse_finish, final_scalar.
// ---------------------------------------------------------------------------

#define BM 128
#define BN 128
#define BKB 128  // K elements (= bytes, fp8) per K-tile

typedef int   i32x8 __attribute__((ext_vector_type(8)));
typedef float f32x4 __attribute__((ext_vector_type(4)));

__device__ __forceinline__ void load_lds16(const void* g, void* l) {
    __builtin_amdgcn_global_load_lds(
        (const __attribute__((address_space(1))) void*)g,
        (__attribute__((address_space(3))) void*)l, 16, 0, 0);
}

// ---- fp8 e4m3fn conversion -------------------------------------------------
__device__ __forceinline__ unsigned char f2e4m3_sw(float x) {
    unsigned u = __float_as_uint(x);
    unsigned s = (u >> 24) & 0x80;
    float ax = __uint_as_float(u & 0x7fffffff);
    if (ax != ax) return (unsigned char)(s | 0x7f);
    if (ax >= 448.f) return (unsigned char)(s | 0x7e);
    if (ax < 0.0009765625f) return (unsigned char)s;      // < 2^-10 -> 0
    if (ax < 0.015625f) {                                 // subnormal, ulp 2^-9
        int n = (int)rintf(ax * 512.f);
        return (unsigned char)(s | n);
    }
    int e = (int)((u >> 23) & 0xff) - 127;
    unsigned m = u & 0x7fffff;
    unsigned keep = m >> 20, rest = m & 0xfffff;
    if (rest > 0x80000u || (rest == 0x80000u && (keep & 1))) keep++;
    if (keep == 8) { keep = 0; e++; if (e > 8) return (unsigned char)(s | 0x7e); }
    return (unsigned char)(s | ((e + 7) << 3) | keep);
}

__device__ __forceinline__ unsigned int pk4_fp8(float a, float b, float c, float d) {
#if __has_builtin(__builtin_amdgcn_cvt_pk_fp8_f32)
    int v = __builtin_amdgcn_cvt_pk_fp8_f32(a, b, 0, false);  // bytes 0,1
    v = __builtin_amdgcn_cvt_pk_fp8_f32(c, d, v, true);       // bytes 2,3
    return (unsigned int)v;
#else
    return (unsigned int)f2e4m3_sw(a) | ((unsigned int)f2e4m3_sw(b) << 8) |
           ((unsigned int)f2e4m3_sw(c) << 16) | ((unsigned int)f2e4m3_sw(d) << 24);
#endif
}

// Combined cast: [0,ne) from e (scale 1), [ne, ne+ncd) from c (scale 16,
// zero-fill past ncs). All boundaries multiples of 8.
__global__ void cast_all_fp8(const float* __restrict__ e,
                             const float* __restrict__ c,
                             unsigned char* __restrict__ e_f8,
                             unsigned char* __restrict__ c_f8,
                             long ne, long ncs, long ncd) {
    long i8 = ((long)blockIdx.x * blockDim.x + threadIdx.x) * 8;
    if (i8 >= ne + ncd) return;
    const float* src;
    unsigned char* dst;
    float scale;
    bool zero = false;
    if (i8 < ne) {
        src = e + i8; dst = e_f8 + i8; scale = 1.0f;
    } else {
        long j8 = i8 - ne;
        dst = c_f8 + j8; scale = 16.0f;
        src = c + j8;
        zero = (j8 + 7 >= ncs);
    }
    uint2 o;
    if (!zero) {
        float4 v0 = *(const float4*)(src);
        float4 v1 = *(const float4*)(src + 4);
        o.x = pk4_fp8(v0.x * scale, v0.y * scale, v0.z * scale, v0.w * scale);
        o.y = pk4_fp8(v1.x * scale, v1.y * scale, v1.z * scale, v1.w * scale);
    } else {
        o.x = o.y = 0u;
    }
    *(uint2*)dst = o;
}

// ---- GEMM 128x128, double-buffered 2-phase, fused LSE epilogue -------------
// E: [N][D] fp8, C: [Vpad][D] fp8 (zero-pad rows).
// LDS: A 2x16KB at [0,32768), B 2x16KB at [32768,65536).
// Row r chunk c (16B) stored at chunk position c^(r&7) (XOR swizzle), achieved
// by pre-swizzling the per-lane GLOBAL source address (linear LDS dest).
// Staging unit: 256 thr x 16B = 4 KB = 32 rows; tile = 4 units. Per wave:
// 4 A-loads + 4 B-loads (vmcnt ops) per K-tile.

// whole A K-tile (4 units of 32 rows)
#define STG_A(k, b) do {                                                      \
    const unsigned char* _s = gA + (size_t)(k) * 128;                         \
    load_lds16(_s,              lA + (b) * 16384);                            \
    load_lds16(_s +     row32,  lA + (b) * 16384 + 4096);                     \
    load_lds16(_s + 2 * row32,  lA + (b) * 16384 + 8192);                     \
    load_lds16(_s + 3 * row32,  lA + (b) * 16384 + 12288);                    \
} while (0)

#define STG_B(k, b) do {                                                      \
    const unsigned char* _s = gB + (size_t)(k) * 128;                         \
    load_lds16(_s,              lB + (b) * 16384);                            \
    load_lds16(_s +     row32,  lB + (b) * 16384 + 4096);                     \
    load_lds16(_s + 2 * row32,  lB + (b) * 16384 + 8192);                     \
    load_lds16(_s + 3 * row32,  lB + (b) * 16384 + 12288);                    \
} while (0)

#define LDA_FRAG(dst, ti, b) do {                                             \
    const unsigned char* _pr = ldsA + (b) * 16384 + (wr0 + (ti) * 16 + lm) * 128; \
    int4 _lo = *(const int4*)(_pr + c0);                                      \
    int4 _hi = *(const int4*)(_pr + c1);                                      \
    dst = (i32x8){_lo.x, _lo.y, _lo.z, _lo.w, _hi.x, _hi.y, _hi.z, _hi.w};    \
} while (0)

#define LDB_FRAG(dst, tj, b) do {                                             \
    const unsigned char* _pr = ldsB + (b) * 16384 + (wc0 + (tj) * 16 + lm) * 128; \
    int4 _lo = *(const int4*)(_pr + c0);                                      \
    int4 _hi = *(const int4*)(_pr + c1);                                      \
    dst = (i32x8){_lo.x, _lo.y, _lo.z, _lo.w, _hi.x, _hi.y, _hi.z, _hi.w};    \
} while (0)

#define MFMA1(a, bfr, c) __builtin_amdgcn_mfma_scale_f32_16x16x128_f8f6f4(    \
    (a), (bfr), (c), 0, 0, 0, sA, 0, sB)

__global__ __launch_bounds__(256, 2)
void gemm_lse_partial(const unsigned char* __restrict__ E,
                      const unsigned char* __restrict__ C,
                      const float* __restrict__ bias,
                      const int* __restrict__ targets,
                      float* __restrict__ row_sum,
                      float* __restrict__ tgt,
                      int N, int D, int V) {
    __shared__ unsigned char smem[65536];
    unsigned char* ldsA = smem;             // 2 x 16 KB
    unsigned char* ldsB = smem + 32768;     // 2 x 16 KB

    const int t_ = threadIdx.x;
    const int w  = t_ >> 6;           // 0..3
    const int l  = t_ & 63;
    const int quad = l >> 4;
    const int lm = l & 15;
    const int wr0 = (w >> 1) * 64;    // 2 row-groups of 64
    const int wc0 = (w & 1) * 64;     // 2 col-groups of 64
    const int c0 = ((quad << 1) ^ (lm & 7)) << 4;
    const int c1 = c0 ^ 16;

    // 2D grid, mt = blockIdx.x (fastest): whole GPU shares one hot B panel;
    // E stays L2/L3-resident. (No XCD swizzle -- data is L3-fit, swizzle
    // privatizes vt ranges per XCD and 8x'd FETCH_SIZE in R8.)
    const int mt = blockIdx.x;
    const int vt = blockIdx.y;
    const int m0 = mt * BM;
    const int v0 = vt * BN;

    // staging map: thread t -> row sr = t>>3 (32 rows/unit), stored chunk t&7
    // (LDS linear per wave: base + lane*16). Global chunk pre-swizzled:
    // gc = (t&7) ^ (sr&7); unit stride 32 rows => (row&7) preserved.
    const int sr = t_ >> 3;                    // 0..31
    const int gc = (t_ & 7) ^ (sr & 7);
    const unsigned char* gA = E + (size_t)(m0 + sr) * D + gc * 16;
    const unsigned char* gB = C + (size_t)(v0 + sr) * D + gc * 16;
    unsigned char* lA = ldsA + w * 1024;       // wave-uniform LDS base
    unsigned char* lB = ldsB + w * 1024;
    const size_t row32 = (size_t)32 * D;

    f32x4 acc[4][4] = {};
    const int sA = 127;  // e8m0 2^0   (E)
    const int sB = 123;  // e8m0 2^-4  (undoes *16 in cast of C)
    const int KT = D / BKB;    // 8 K-tiles

    // ---- prologue: K-tile 0 into buf0 --------------------------------------
    STG_A(0, 0); STG_B(0, 0);
    asm volatile("s_waitcnt vmcnt(0)" ::: "memory");
    __builtin_amdgcn_s_barrier();
    asm volatile("" ::: "memory");

    // ---- main loop: issue-early stage, compute, cheap drain ----------------
    int buf = 0;
    for (int kt = 0; kt < KT; ++kt) {
        const bool more = (kt < KT - 1);
        if (more) { STG_A(kt + 1, buf ^ 1); STG_B(kt + 1, buf ^ 1); }

        i32x8 af0, af1, af2, af3, bf0, bf1, bf2, bf3;
        LDA_FRAG(af0, 0, buf); LDA_FRAG(af1, 1, buf);
        LDA_FRAG(af2, 2, buf); LDA_FRAG(af3, 3, buf);
        LDB_FRAG(bf0, 0, buf); LDB_FRAG(bf1, 1, buf);
        LDB_FRAG(bf2, 2, buf); LDB_FRAG(bf3, 3, buf);

        asm volatile("s_waitcnt lgkmcnt(0)" ::: "memory");
        __builtin_amdgcn_sched_barrier(0);
        __builtin_amdgcn_s_setprio(1);
        acc[0][0] = MFMA1(af0, bf0, acc[0][0]);
        acc[0][1] = MFMA1(af0, bf1, acc[0][1]);
        acc[0][2] = MFMA1(af0, bf2, acc[0][2]);
        acc[0][3] = MFMA1(af0, bf3, acc[0][3]);
        acc[1][0] = MFMA1(af1, bf0, acc[1][0]);
        acc[1][1] = MFMA1(af1, bf1, acc[1][1]);
        acc[1][2] = MFMA1(af1, bf2, acc[1][2]);
        acc[1][3] = MFMA1(af1, bf3, acc[1][3]);
        acc[2][0] = MFMA1(af2, bf0, acc[2][0]);
        acc[2][1] = MFMA1(af2, bf1, acc[2][1]);
        acc[2][2] = MFMA1(af2, bf2, acc[2][2]);
        acc[2][3] = MFMA1(af2, bf3, acc[2][3]);
        acc[3][0] = MFMA1(af3, bf0, acc[3][0]);
        acc[3][1] = MFMA1(af3, bf1, acc[3][1]);
        acc[3][2] = MFMA1(af3, bf2, acc[3][2]);
        acc[3][3] = MFMA1(af3, bf3, acc[3][3]);
        __builtin_amdgcn_s_setprio(0);
        __builtin_amdgcn_sched_barrier(0);

        if (more) {
            // stage loads were issued ~1 K-tile of compute ago -> cheap drain
            asm volatile("s_waitcnt vmcnt(0)" ::: "memory");
            __builtin_amdgcn_s_barrier();
            asm volatile("" ::: "memory");
            buf ^= 1;
        }
    }

    // ---- epilogue: bias + exp + target extraction + per-row sums -----------
    // acc[ti][tj][r] -> row = wr0+ti*16+quad*4+r, col = wc0+tj*16+lm
    __syncthreads();                 // all LDS reads done; re-alias tile LDS
    float* red = (float*)smem;       // [2 col-wave-groups][128 rows]

    float bv[4];
#pragma unroll
    for (int tj = 0; tj < 4; tj++) {
        int col = v0 + wc0 + tj * 16 + lm;
        bv[tj] = (col < V) ? bias[col] : -INFINITY;
    }
#pragma unroll
    for (int ti = 0; ti < 4; ti++) {
#pragma unroll
        for (int r = 0; r < 4; r++) {
            const int rl = wr0 + ti * 16 + quad * 4 + r;
            const int tl = targets[m0 + rl] - v0 - wc0;
            float s = 0.f;
#pragma unroll
            for (int tj = 0; tj < 4; tj++) {
                float v = acc[ti][tj][r] + bv[tj];   // pad col: exp(-inf)=0
                s += __expf(v);
                if (tj * 16 + lm == tl) tgt[m0 + rl] = v;
            }
#pragma unroll
            for (int off = 1; off < 16; off <<= 1)
                s += __shfl_xor(s, off, 64);
            if (lm == 0) red[(w & 1) * 128 + rl] = s;
        }
    }
    __syncthreads();
    if (t_ < BM)
        atomicAdd(&row_sum[m0 + t_], red[t_] + red[128 + t_]);
}

// Finish: nll per row, block-reduce, atomic accumulate (sum, count).
__global__ void lse_finish(const float* __restrict__ row_sum,
                           const float* __restrict__ tgt,
                           const int* __restrict__ targets,
                           float* __restrict__ gacc, int N) {
    __shared__ float sred[8];
    int r = blockIdx.x * 256 + threadIdx.x;
    float nll = 0.f, cnt = 0.f;
    if (r < N) {
        int tg = targets[r];
        if (tg != -100) { nll = logf(row_sum[r]) - tgt[r]; cnt = 1.f; }
    }
#pragma unroll
    for (int off = 32; off; off >>= 1) {
        nll += __shfl_xor(nll, off, 64);
        cnt += __shfl_xor(cnt, off, 64);
    }
    int w = threadIdx.x >> 6, l = threadIdx.x & 63;
    if (l == 0) { sred[w] = nll; sred[4 + w] = cnt; }
    __syncthreads();
    if (threadIdx.x == 0) {
        atomicAdd(gacc, sred[0] + sred[1] + sred[2] + sred[3]);
        atomicAdd(gacc + 1, sred[4] + sred[5] + sred[6] + sred[7]);
    }
}

__global__ void final_scalar(const float* __restrict__ gacc, float* __restrict__ out) {
    out[0] = gacc[0] / fmaxf(gacc[1], 1.f);
}

extern "C" void kernel_launch(void* const* d_in, const int* in_sizes, int n_in,
                              void* d_out, int out_size, void* d_ws, size_t ws_size,
                              hipStream_t stream) {
    const float* e       = (const float*)d_in[0];
    const float* c       = (const float*)d_in[1];
    const int*   targets = (const int*)d_in[2];
    const float* bias    = (const float*)d_in[3];
    float* out = (float*)d_out;

    const int N = in_sizes[2];            // 8192
    const int V = in_sizes[3];            // 50257
    const int D = in_sizes[0] / N;        // 1024
    const int mtiles = N / BM;            // 64
    const int vtiles = (V + BN - 1) / BN; // 393
    const long Vpad = (long)vtiles * BN;  // 50304

    char* ws = (char*)d_ws;
    size_t off = 0;
    auto alloc = [&](size_t bytes) {
        void* p = ws + off;
        off += (bytes + 255) & ~(size_t)255;
        return p;
    };
    unsigned char* e_f8 = (unsigned char*)alloc((size_t)N * D);
    unsigned char* c_f8 = (unsigned char*)alloc((size_t)Vpad * D);
    float* row_sum = (float*)alloc((size_t)N * 4);   // zeroed below
    float* gacc    = (float*)alloc(8);               // adjacent to row_sum
    float* tgt     = (float*)alloc((size_t)N * 4);

    // one memset covers row_sum (N*4, 256-rounded) + gacc
    hipMemsetAsync(row_sum, 0, (size_t)N * 4 + 256 + 8, stream);

    const long ne  = (long)N * D;
    const long ncs = (long)V * D;
    const long ncd = Vpad * D;
    const long tot8 = (ne + ncd) / 8;
    cast_all_fp8<<<(int)((tot8 + 255) / 256), 256, 0, stream>>>(
        e, c, e_f8, c_f8, ne, ncs, ncd);

    dim3 grid(mtiles, vtiles);
    gemm_lse_partial<<<grid, 256, 0, stream>>>(e_f8, c_f8, bias, targets,
                                               row_sum, tgt, N, D, V);

    lse_finish<<<(N + 255) / 256, 256, 0, stream>>>(row_sum, tgt, targets, gacc, N);
    final_scalar<<<1, 1, 0, stream>>>(gacc, out);
}